// Round 21
// baseline (73.032 us; speedup 1.0000x reference)
//
#include <hip/hip_runtime.h>

#define BB 16
#define CH 256
#define NH 4
#define DH 64
#define NN 1024

typedef _Float16 f16x8 __attribute__((ext_vector_type(8)));
typedef float f32x4 __attribute__((ext_vector_type(4)));
typedef float f32x16 __attribute__((ext_vector_type(16)));
typedef unsigned int uint32x4 __attribute__((ext_vector_type(4)));

__device__ __forceinline__ unsigned short f2h(float x) {
    _Float16 h = (_Float16)x;
    return __builtin_bit_cast(unsigned short, h);
}

__device__ __forceinline__ unsigned cvtpk(float a, float b) {
    auto r = __builtin_amdgcn_cvt_pkrtz(a, b);      // low half = a, high = b
    return __builtin_bit_cast(unsigned, r);
}

// ---------------- merged: x-transpose (blocks 0..4095) + W->fp16 (blocks 4096..4863) ----------------
__global__ __launch_bounds__(256) void prepxt_kernel(
    const float* __restrict__ x,
    const float* __restrict__ Wq, const float* __restrict__ Wk, const float* __restrict__ Wv,
    unsigned short* __restrict__ xT, unsigned short* __restrict__ Wh)
{
    const int bid = blockIdx.x;
    const int t = threadIdx.x;
    if (bid < 4096) {
        const int b = bid >> 8, c0 = ((bid >> 5) & 7) * 32, n0 = (bid & 31) * 32;
        __shared__ float T[32][33];
        {
            int c = t >> 3, n4 = (t & 7) * 4;
            float4 v4 = *(const float4*)&x[((size_t)b * CH + c0 + c) * NN + n0 + n4];
            T[c][n4 + 0] = v4.x; T[c][n4 + 1] = v4.y;
            T[c][n4 + 2] = v4.z; T[c][n4 + 3] = v4.w;
        }
        __syncthreads();
        {
            int n = t >> 3, c4 = (t & 7) * 4;
            ushort4 o;
            o.x = f2h(T[c4 + 0][n]); o.y = f2h(T[c4 + 1][n]);
            o.z = f2h(T[c4 + 2][n]); o.w = f2h(T[c4 + 3][n]);
            *(ushort4*)&xT[((size_t)b * NN + n0 + n) * CH + c0 + c4] = o;
        }
    } else {
        int idx = (bid - 4096) * 256 + t;           // 3*CH*CH = 196608
        if (idx >= 3 * CH * CH) return;
        int p = idx >> 16, oc = idx & 65535;
        const float* W = (p == 0) ? Wq : ((p == 1) ? Wk : Wv);
        Wh[idx] = f2h(W[oc]);
    }
}

// ---------------- projection + fused frag-major repack (R13-verified, ~13us) ----------------
// Img address bijections (R13-verified):
//   Kb(j',dd,is_q): j'*128 + (((dd>>3)+8*is_q) ^ (j'&15))<<3) + (dd&7)
//   Vb(d,j'): vc=j'>>3, c4=(j'>>2)&1, c=j'&3, vM=((vc>>1)<<2)+(vc&1)+((d>>5)<<4);
//             (d&31)*128 + ((((vM>>1)+c4) ^ (d&15))<<3) + ((vM&1)<<2) + c
__global__ __launch_bounds__(256) void proj_kernel(
    const unsigned short* __restrict__ xT,
    const unsigned short* __restrict__ Wh,
    const float* __restrict__ bq, const float* __restrict__ bk, const float* __restrict__ bv,
    unsigned short* __restrict__ kF, unsigned short* __restrict__ vF)
{
    const int bz = blockIdx.z;
    const int b = bz / 3, p = bz % 3;
    const int jt = blockIdx.x;          // n-tile
    const int ot = blockIdx.y;          // o-tile == head
    const int n0 = jt * 64;
    const int o0 = ot * 64;
    const float* bias = (p == 0) ? bq : ((p == 1) ? bk : bv);

    __shared__ __align__(16) unsigned short Xs[64][72];
    __shared__ __align__(16) unsigned short Whs[64][72];
    __shared__ __align__(16) unsigned short Img[8192];     // 16 KB frag image

    const int tid = threadIdx.x;
    const int wid = tid >> 6, lane = tid & 63;
    const int g = lane >> 4, lr = lane & 15;
    const int l31 = lane & 31, hi = lane >> 5;

    const unsigned short* xb  = xT + (size_t)b * NN * CH;
    const unsigned short* Whp = Wh + (size_t)p * CH * CH;

    const f32x4 z4 = {0.f, 0.f, 0.f, 0.f};
    f32x4 acc[4] = {z4, z4, z4, z4};

    for (int cs = 0; cs < 4; ++cs) {
        const int c0 = cs * 64;
        __syncthreads();
        #pragma unroll
        for (int rep = 0; rep < 2; ++rep) {
            int f = rep * 256 + tid;
            int r = f >> 3, s = f & 7;
            *(uint4*)&Xs[r][s * 8]  = *(const uint4*)&xb[(size_t)(n0 + r) * CH + c0 + s * 8];
            *(uint4*)&Whs[r][s * 8] = *(const uint4*)&Whp[(size_t)(o0 + r) * CH + c0 + s * 8];
        }
        __syncthreads();
        #pragma unroll
        for (int ks = 0; ks < 2; ++ks) {
            f16x8 ah = *(const f16x8*)&Whs[wid * 16 + lr][ks * 32 + g * 8];
            #pragma unroll
            for (int fc = 0; fc < 4; ++fc) {
                f16x8 bx = *(const f16x8*)&Xs[fc * 16 + lr][ks * 32 + g * 8];
                acc[fc] = __builtin_amdgcn_mfma_f32_16x16x32_f16(ah, bx, acc[fc], 0, 0, 0);
            }
        }
    }

    float bb[4];
    #pragma unroll
    for (int rr = 0; rr < 4; ++rr) bb[rr] = bias[o0 + wid * 16 + g * 4 + rr];

    const int bh = b * NH + ot;
    __syncthreads();    // all MFMA reads of Whs/Xs complete before Img overwrite

    if (p < 2) {
        const float scale = (p == 0) ? 1.44269504088896f : 1.0f;   // fold log2e into q
        const int qoff = (p == 0) ? 8 : 0;
        #pragma unroll
        for (int fc = 0; fc < 4; ++fc)
            #pragma unroll
            for (int rr = 0; rr < 4; ++rr) {
                int jl = fc * 16 + lr;
                int dd = wid * 16 + g * 4 + rr;
                Img[jl * 128 + ((((dd >> 3) + qoff) ^ (jl & 15)) << 3) + (dd & 7)] =
                    f2h((acc[fc][rr] + bb[rr]) * scale);
            }
        __syncthreads();
        const int ks = ((p == 0) ? 4 : 0) + wid;
        #pragma unroll
        for (int grp = 0; grp < 2; ++grp) {
            int row = grp * 32 + l31;
            int slot = ks * 2 + hi;
            uint4 v = *(const uint4*)&Img[row * 128 + ((slot ^ (row & 15)) << 3)];
            size_t dst = ((((size_t)bh * 16 + jt) * 8 + ks) * 2 + grp) * 512 + (size_t)lane * 8;
            *(uint4*)&kF[dst] = v;
        }
    } else {
        #pragma unroll
        for (int fc = 0; fc < 4; ++fc)
            #pragma unroll
            for (int rr = 0; rr < 4; ++rr) {
                int d  = wid * 16 + g * 4 + rr;
                int jl = fc * 16 + lr;
                int vc = jl >> 3, c4 = (jl >> 2) & 1, c = jl & 3;
                int vM = ((vc >> 1) << 2) + (vc & 1) + ((d >> 5) << 4);
                Img[(d & 31) * 128 + ((((vM >> 1) + c4) ^ (d & 15)) << 3) + ((vM & 1) << 2) + c] =
                    f2h(acc[fc][rr] + bb[rr]);
            }
        __syncthreads();
        const int u = wid;
        #pragma unroll
        for (int which = 0; which < 2; ++which) {
            int slot = which * 8 + u * 2 + hi;
            int row = l31;
            uint4 v = *(const uint4*)&Img[row * 128 + ((slot ^ (row & 15)) << 3)];
            size_t dst = ((((size_t)bh * 16 + jt) * 4 + u) * 2 + which) * 512 + (size_t)lane * 8;
            *(uint4*)&vF[dst] = v;
        }
    }
}

// ---------------- fused flash attention: split K-prefetch ----------------
// R19 spilled (two full K-sets ~270 regs > 256 cap). Split scheme needs ONE extra
// half-set (~220 total): kP (a0-half of tile t) prefetched under t-1's softmax+PV;
// a1-half issued at iter top and covered by the s0-chain's ~250-300cyc of MFMAs
// (s0 runs first, on ready kP). V unchanged (covered by QK+softmax). Numerics
// bit-identical to R20. Spill tripwire = WRITE_SIZE.
__global__ __launch_bounds__(256, 2) void attn_kernel(
    const unsigned short* __restrict__ kF, const unsigned short* __restrict__ vF,
    const float* __restrict__ rel_h, const float* __restrict__ rel_w,
    float* __restrict__ out)
{
    const int wg = blockIdx.x;                       // 0..511
    const int bh = (wg & 7) * 8 + ((wg >> 3) & 7);   // XCD-bijective: 8 (b,h) per XCD
    const int it = wg >> 6;                          // 0..7
    const int b = bh >> 2, h = bh & 3;
    const int i0 = it * 128;

    __shared__ __align__(16) float Epi[64 * 132];    // 33.8 KB epilogue transpose
    __shared__ __align__(16) float Lbuf[128];
    __shared__ float ScBuf[4][32];

    const int tid = threadIdx.x;
    const int wid = tid >> 6, lane = tid & 63;
    const int l31 = lane & 31, hi = lane >> 5;

    const unsigned short* kFb = kF + (size_t)bh * 16 * 8192 + (size_t)lane * 8;
    const unsigned short* vFb = vF + (size_t)bh * 16 * 4096 + (size_t)lane * 8;

    // Q-ext B-fragments: q*log2e from kF chunks (coalesced); pos inline from rel arrays
    f16x8 bQ[8];
    {
        const int i = i0 + wid * 32 + l31;
        const int iw = i >> 5, ih = i & 31;
        const unsigned short* qck = kFb + (size_t)(it * 2 + (wid >> 1)) * 8192;
        #pragma unroll
        for (int ksp = 0; ksp < 4; ++ksp) {
            bQ[ksp] = *(const f16x8*)(qck + (((4 + ksp) * 2 + (wid & 1)) * 512));
            int d0 = ksp * 16 + hi * 8;
            f16x8 pp;
            #pragma unroll
            for (int e = 0; e < 8; ++e) {
                int d = d0 + e;
                pp[e] = (_Float16)(rel_w[(h * 64 + d) * 32 + iw] + rel_h[(h * 64 + d) * 32 + ih]);
            }
            bQ[4 + ksp] = pp;
        }
    }

    f32x16 O0 = {}, O1 = {};
    float m_run = -1e30f, l_run = 0.f;

    // prefetch tile 0's a0-half
    f16x8 kP[8];
    #pragma unroll
    for (int ks = 0; ks < 8; ++ks)
        kP[ks] = *(const f16x8*)(kFb + ks * 1024);

    for (int t = 0; t < 16; ++t) {
        const unsigned short* kt = kFb + (size_t)t * 8192;
        const unsigned short* vt = vFb + (size_t)t * 4096;

        // ---- issue this tile's a1-half + V frags (a1 covered by s0-chain; V by QK+softmax) ----
        f16x8 a1[8];
        #pragma unroll
        for (int ks = 0; ks < 8; ++ks)
            a1[ks] = *(const f16x8*)(kt + ks * 1024 + 512);
        f16x8 vf0[4], vf1[4];
        #pragma unroll
        for (int u = 0; u < 4; ++u) {
            vf0[u] = *(const f16x8*)(vt + u * 1024);
            vf1[u] = *(const f16x8*)(vt + u * 1024 + 512);
        }

        // ---- QK^T: s0-chain first (kP ready), then s1-chain (a1 arrived meanwhile) ----
        f32x16 s0 = {}, s1 = {};
        __builtin_amdgcn_s_setprio(1);
        #pragma unroll
        for (int ks = 0; ks < 8; ++ks)
            s0 = __builtin_amdgcn_mfma_f32_32x32x16_f16(kP[ks], bQ[ks], s0, 0, 0, 0);
        #pragma unroll
        for (int ks = 0; ks < 8; ++ks)
            s1 = __builtin_amdgcn_mfma_f32_32x32x16_f16(a1[ks], bQ[ks], s1, 0, 0, 0);
        __builtin_amdgcn_s_setprio(0);

        // ---- prefetch t+1's a0-half (hidden under softmax+PV) ----
        if (t < 15) {
            const unsigned short* kn = kt + 8192;
            #pragma unroll
            for (int ks = 0; ks < 8; ++ks)
                kP[ks] = *(const f16x8*)(kn + ks * 1024);
        }

        // ---- defer-max online softmax (log2 domain), fully in-lane ----
        float fm = s0[0];
        #pragma unroll
        for (int r = 1; r < 16; ++r) fm = fmaxf(fm, s0[r]);
        #pragma unroll
        for (int r = 0; r < 16; ++r) fm = fmaxf(fm, s1[r]);

        if (!__all(fm <= m_run + 8.f)) {
            float fmf = fmaxf(fm, __shfl_xor(fm, 32));   // pair-lane: full row max
            float mn = fmaxf(m_run, fmf);
            float sc = exp2f(m_run - mn);
            m_run = mn;
            l_run *= sc;
            if (lane < 32) ScBuf[wid][lane] = sc;        // sc for softmax row i = lane
            #pragma unroll
            for (int r = 0; r < 16; ++r) {
                int irow = (r & 3) + 8 * (r >> 2) + 4 * hi;
                float scv = ScBuf[wid][irow];
                O0[r] *= scv; O1[r] *= scv;
            }
        }

        // ---- P = exp2(S - m): pack fp16 pairs, sum in-lane ----
        unsigned c0[8], c1[8];
        float ps = 0.f;
        #pragma unroll
        for (int m = 0; m < 8; ++m) {
            float pa = exp2f(s0[2 * m]     - m_run);
            float pb = exp2f(s0[2 * m + 1] - m_run);
            float pc = exp2f(s1[2 * m]     - m_run);
            float pd = exp2f(s1[2 * m + 1] - m_run);
            ps += (pa + pb) + (pc + pd);
            c0[m] = cvtpk(pa, pb);
            c1[m] = cvtpk(pc, pd);
        }
        l_run += ps;

        // ---- PV A-frags: lane's own words, zero exchange ----
        f16x8 pA[2][2];
        #pragma unroll
        for (int js = 0; js < 2; ++js) {
            unsigned* c = js ? c1 : c0;
            #pragma unroll
            for (int ksi = 0; ksi < 2; ++ksi) {
                uint32x4 w = { c[ksi * 4 + 0], c[ksi * 4 + 1], c[ksi * 4 + 2], c[ksi * 4 + 3] };
                pA[js][ksi] = __builtin_bit_cast(f16x8, w);
            }
        }

        // ---- PV: O[i][d] += P * V  (u = js*2 + ksi) ----
        __builtin_amdgcn_s_setprio(1);
        #pragma unroll
        for (int js = 0; js < 2; ++js) {
            #pragma unroll
            for (int ksi = 0; ksi < 2; ++ksi) {
                int u = js * 2 + ksi;
                O0 = __builtin_amdgcn_mfma_f32_32x32x16_f16(pA[js][ksi], vf0[u], O0, 0, 0, 0);
                O1 = __builtin_amdgcn_mfma_f32_32x32x16_f16(pA[js][ksi], vf1[u], O1, 0, 0, 0);
            }
        }
        __builtin_amdgcn_s_setprio(0);
    }

    // ---- epilogue: pair-sum l, LDS transpose, normalized coalesced store ----
    float l_full = l_run + __shfl_xor(l_run, 32);
    float invl = 1.0f / l_full;
    if (lane < 32) Lbuf[wid * 32 + lane] = invl;
    #pragma unroll
    for (int r = 0; r < 16; ++r) {
        int irow = (r & 3) + 8 * (r >> 2) + 4 * hi;
        int ilocal = wid * 32 + irow;
        Epi[(l31) * 132 + ilocal]      = O0[r];
        Epi[(32 + l31) * 132 + ilocal] = O1[r];
    }
    __syncthreads();
    float* ob = out + ((size_t)b * CH + h * DH) * NN + i0;
    #pragma unroll
    for (int rep = 0; rep < 8; ++rep) {
        int f = rep * 256 + tid;
        int d = f >> 5, q = f & 31;
        float4 v4 = *(const float4*)&Epi[d * 132 + q * 4];
        float4 iv = *(const float4*)&Lbuf[q * 4];
        v4.x *= iv.x; v4.y *= iv.y; v4.z *= iv.z; v4.w *= iv.w;
        *(float4*)&ob[(size_t)d * NN + q * 4] = v4;
    }
}

extern "C" void kernel_launch(void* const* d_in, const int* in_sizes, int n_in,
                              void* d_out, int out_size, void* d_ws, size_t ws_size,
                              hipStream_t stream) {
    const float* x     = (const float*)d_in[0];
    const float* Wq    = (const float*)d_in[1];
    const float* bq    = (const float*)d_in[2];
    const float* Wk    = (const float*)d_in[3];
    const float* bk    = (const float*)d_in[4];
    const float* Wv    = (const float*)d_in[5];
    const float* bv    = (const float*)d_in[6];
    const float* rel_h = (const float*)d_in[7];
    const float* rel_w = (const float*)d_in[8];
    // d_in[9] (reg_qk), d_in[10] (reg_v): dead — reference discards the register-token group.
    float* out = (float*)d_out;

    unsigned short* kF = (unsigned short*)d_ws;                 // 8,388,608 halves (16.8MB)
    unsigned short* vF = kF + (size_t)8388608;                  // 4,194,304 (8.4MB)
    unsigned short* xT = vF + (size_t)4194304;                  // 4,194,304 (8.4MB)
    unsigned short* Wh = xT + (size_t)4194304;                  // 196,608 — 34.0MB total

    prepxt_kernel<<<dim3(4096 + 768), 256, 0, stream>>>(x, Wq, Wk, Wv, xT, Wh);
    proj_kernel<<<dim3(16, 4, 48), 256, 0, stream>>>(
        xT, Wh, bq, bk, bv, kF, vF);
    attn_kernel<<<dim3(512), 256, 0, stream>>>(kF, vF, rel_h, rel_w, out);
}

// Round 22
// 71.622 us; speedup vs baseline: 1.0197x; 1.0197x over previous
//
#include <hip/hip_runtime.h>

#define BB 16
#define CH 256
#define NH 4
#define DH 64
#define NN 1024

typedef _Float16 f16x8 __attribute__((ext_vector_type(8)));
typedef float f32x4 __attribute__((ext_vector_type(4)));
typedef float f32x16 __attribute__((ext_vector_type(16)));
typedef unsigned int uint32x4 __attribute__((ext_vector_type(4)));

__device__ __forceinline__ unsigned short f2h(float x) {
    _Float16 h = (_Float16)x;
    return __builtin_bit_cast(unsigned short, h);
}

__device__ __forceinline__ unsigned cvtpk(float a, float b) {
    auto r = __builtin_amdgcn_cvt_pkrtz(a, b);      // low half = a, high = b
    return __builtin_bit_cast(unsigned, r);
}

// ---------------- merged: x-transpose (blocks 0..4095) + W->fp16 (blocks 4096..4863) ----------------
__global__ __launch_bounds__(256) void prepxt_kernel(
    const float* __restrict__ x,
    const float* __restrict__ Wq, const float* __restrict__ Wk, const float* __restrict__ Wv,
    unsigned short* __restrict__ xT, unsigned short* __restrict__ Wh)
{
    const int bid = blockIdx.x;
    const int t = threadIdx.x;
    if (bid < 4096) {
        const int b = bid >> 8, c0 = ((bid >> 5) & 7) * 32, n0 = (bid & 31) * 32;
        __shared__ float T[32][33];
        {
            int c = t >> 3, n4 = (t & 7) * 4;
            float4 v4 = *(const float4*)&x[((size_t)b * CH + c0 + c) * NN + n0 + n4];
            T[c][n4 + 0] = v4.x; T[c][n4 + 1] = v4.y;
            T[c][n4 + 2] = v4.z; T[c][n4 + 3] = v4.w;
        }
        __syncthreads();
        {
            int n = t >> 3, c4 = (t & 7) * 4;
            ushort4 o;
            o.x = f2h(T[c4 + 0][n]); o.y = f2h(T[c4 + 1][n]);
            o.z = f2h(T[c4 + 2][n]); o.w = f2h(T[c4 + 3][n]);
            *(ushort4*)&xT[((size_t)b * NN + n0 + n) * CH + c0 + c4] = o;
        }
    } else {
        int idx = (bid - 4096) * 256 + t;           // 3*CH*CH = 196608
        if (idx >= 3 * CH * CH) return;
        int p = idx >> 16, oc = idx & 65535;
        const float* W = (p == 0) ? Wq : ((p == 1) ? Wk : Wv);
        Wh[idx] = f2h(W[oc]);
    }
}

// ---------------- projection + fused frag-major repack (R13-verified, ~13us) ----------------
// Img address bijections (R13-verified):
//   Kb(j',dd,is_q): j'*128 + (((dd>>3)+8*is_q) ^ (j'&15))<<3) + (dd&7)
//   Vb(d,j'): vc=j'>>3, c4=(j'>>2)&1, c=j'&3, vM=((vc>>1)<<2)+(vc&1)+((d>>5)<<4);
//             (d&31)*128 + ((((vM>>1)+c4) ^ (d&15))<<3) + ((vM&1)<<2) + c
__global__ __launch_bounds__(256) void proj_kernel(
    const unsigned short* __restrict__ xT,
    const unsigned short* __restrict__ Wh,
    const float* __restrict__ bq, const float* __restrict__ bk, const float* __restrict__ bv,
    unsigned short* __restrict__ kF, unsigned short* __restrict__ vF)
{
    const int bz = blockIdx.z;
    const int b = bz / 3, p = bz % 3;
    const int jt = blockIdx.x;          // n-tile
    const int ot = blockIdx.y;          // o-tile == head
    const int n0 = jt * 64;
    const int o0 = ot * 64;
    const float* bias = (p == 0) ? bq : ((p == 1) ? bk : bv);

    __shared__ __align__(16) unsigned short Xs[64][72];
    __shared__ __align__(16) unsigned short Whs[64][72];
    __shared__ __align__(16) unsigned short Img[8192];     // 16 KB frag image

    const int tid = threadIdx.x;
    const int wid = tid >> 6, lane = tid & 63;
    const int g = lane >> 4, lr = lane & 15;
    const int l31 = lane & 31, hi = lane >> 5;

    const unsigned short* xb  = xT + (size_t)b * NN * CH;
    const unsigned short* Whp = Wh + (size_t)p * CH * CH;

    const f32x4 z4 = {0.f, 0.f, 0.f, 0.f};
    f32x4 acc[4] = {z4, z4, z4, z4};

    for (int cs = 0; cs < 4; ++cs) {
        const int c0 = cs * 64;
        __syncthreads();
        #pragma unroll
        for (int rep = 0; rep < 2; ++rep) {
            int f = rep * 256 + tid;
            int r = f >> 3, s = f & 7;
            *(uint4*)&Xs[r][s * 8]  = *(const uint4*)&xb[(size_t)(n0 + r) * CH + c0 + s * 8];
            *(uint4*)&Whs[r][s * 8] = *(const uint4*)&Whp[(size_t)(o0 + r) * CH + c0 + s * 8];
        }
        __syncthreads();
        #pragma unroll
        for (int ks = 0; ks < 2; ++ks) {
            f16x8 ah = *(const f16x8*)&Whs[wid * 16 + lr][ks * 32 + g * 8];
            #pragma unroll
            for (int fc = 0; fc < 4; ++fc) {
                f16x8 bx = *(const f16x8*)&Xs[fc * 16 + lr][ks * 32 + g * 8];
                acc[fc] = __builtin_amdgcn_mfma_f32_16x16x32_f16(ah, bx, acc[fc], 0, 0, 0);
            }
        }
    }

    float bb[4];
    #pragma unroll
    for (int rr = 0; rr < 4; ++rr) bb[rr] = bias[o0 + wid * 16 + g * 4 + rr];

    const int bh = b * NH + ot;
    __syncthreads();    // all MFMA reads of Whs/Xs complete before Img overwrite

    if (p < 2) {
        const float scale = (p == 0) ? 1.44269504088896f : 1.0f;   // fold log2e into q
        const int qoff = (p == 0) ? 8 : 0;
        #pragma unroll
        for (int fc = 0; fc < 4; ++fc)
            #pragma unroll
            for (int rr = 0; rr < 4; ++rr) {
                int jl = fc * 16 + lr;
                int dd = wid * 16 + g * 4 + rr;
                Img[jl * 128 + ((((dd >> 3) + qoff) ^ (jl & 15)) << 3) + (dd & 7)] =
                    f2h((acc[fc][rr] + bb[rr]) * scale);
            }
        __syncthreads();
        const int ks = ((p == 0) ? 4 : 0) + wid;
        #pragma unroll
        for (int grp = 0; grp < 2; ++grp) {
            int row = grp * 32 + l31;
            int slot = ks * 2 + hi;
            uint4 v = *(const uint4*)&Img[row * 128 + ((slot ^ (row & 15)) << 3)];
            size_t dst = ((((size_t)bh * 16 + jt) * 8 + ks) * 2 + grp) * 512 + (size_t)lane * 8;
            *(uint4*)&kF[dst] = v;
        }
    } else {
        #pragma unroll
        for (int fc = 0; fc < 4; ++fc)
            #pragma unroll
            for (int rr = 0; rr < 4; ++rr) {
                int d  = wid * 16 + g * 4 + rr;
                int jl = fc * 16 + lr;
                int vc = jl >> 3, c4 = (jl >> 2) & 1, c = jl & 3;
                int vM = ((vc >> 1) << 2) + (vc & 1) + ((d >> 5) << 4);
                Img[(d & 31) * 128 + ((((vM >> 1) + c4) ^ (d & 15)) << 3) + ((vM & 1) << 2) + c] =
                    f2h(acc[fc][rr] + bb[rr]);
            }
        __syncthreads();
        const int u = wid;
        #pragma unroll
        for (int which = 0; which < 2; ++which) {
            int slot = which * 8 + u * 2 + hi;
            int row = l31;
            uint4 v = *(const uint4*)&Img[row * 128 + ((slot ^ (row & 15)) << 3)];
            size_t dst = ((((size_t)bh * 16 + jt) * 4 + u) * 2 + which) * 512 + (size_t)lane * 8;
            *(uint4*)&vF[dst] = v;
        }
    }
}

// ---------------- fused flash attention (R14/R17/R20-verified 256-thr form, ~50.4us) ----------------
// Barrier-free main loop, frag-major coalesced global loads, in-register softmax,
// zero-exchange PV. pos B-frags computed inline from rel_w/rel_h.
__global__ __launch_bounds__(256, 2) void attn_kernel(
    const unsigned short* __restrict__ kF, const unsigned short* __restrict__ vF,
    const float* __restrict__ rel_h, const float* __restrict__ rel_w,
    float* __restrict__ out)
{
    const int wg = blockIdx.x;                       // 0..511
    const int bh = (wg & 7) * 8 + ((wg >> 3) & 7);   // XCD-bijective: 8 (b,h) per XCD
    const int it = wg >> 6;                          // 0..7
    const int b = bh >> 2, h = bh & 3;
    const int i0 = it * 128;

    __shared__ __align__(16) float Epi[64 * 132];    // 33.8 KB epilogue transpose
    __shared__ __align__(16) float Lbuf[128];
    __shared__ float ScBuf[4][32];

    const int tid = threadIdx.x;
    const int wid = tid >> 6, lane = tid & 63;
    const int l31 = lane & 31, hi = lane >> 5;

    const unsigned short* kFb = kF + (size_t)bh * 16 * 8192 + (size_t)lane * 8;
    const unsigned short* vFb = vF + (size_t)bh * 16 * 4096 + (size_t)lane * 8;

    // Q-ext B-fragments: q*log2e from kF chunks (coalesced); pos inline from rel arrays
    f16x8 bQ[8];
    {
        const int i = i0 + wid * 32 + l31;
        const int iw = i >> 5, ih = i & 31;
        const unsigned short* qck = kFb + (size_t)(it * 2 + (wid >> 1)) * 8192;
        #pragma unroll
        for (int ksp = 0; ksp < 4; ++ksp) {
            bQ[ksp] = *(const f16x8*)(qck + (((4 + ksp) * 2 + (wid & 1)) * 512));
            int d0 = ksp * 16 + hi * 8;
            f16x8 pp;
            #pragma unroll
            for (int e = 0; e < 8; ++e) {
                int d = d0 + e;
                pp[e] = (_Float16)(rel_w[(h * 64 + d) * 32 + iw] + rel_h[(h * 64 + d) * 32 + ih]);
            }
            bQ[4 + ksp] = pp;
        }
    }

    f32x16 O0 = {}, O1 = {};
    float m_run = -1e30f, l_run = 0.f;

    for (int t = 0; t < 16; ++t) {
        const unsigned short* kt = kFb + (size_t)t * 8192;
        const unsigned short* vt = vFb + (size_t)t * 4096;

        // ---- issue all 24 frag loads (independent; coalesced 16B/lane) ----
        f16x8 a0[8], a1[8];
        #pragma unroll
        for (int ks = 0; ks < 8; ++ks) {
            a0[ks] = *(const f16x8*)(kt + ks * 1024);
            a1[ks] = *(const f16x8*)(kt + ks * 1024 + 512);
        }
        f16x8 vf0[4], vf1[4];
        #pragma unroll
        for (int u = 0; u < 4; ++u) {
            vf0[u] = *(const f16x8*)(vt + u * 1024);
            vf1[u] = *(const f16x8*)(vt + u * 1024 + 512);
        }

        // ---- QK^T (swapped): two 32x32 S^T subtiles ----
        f32x16 s0 = {}, s1 = {};
        __builtin_amdgcn_s_setprio(1);
        #pragma unroll
        for (int ks = 0; ks < 8; ++ks) {
            s0 = __builtin_amdgcn_mfma_f32_32x32x16_f16(a0[ks], bQ[ks], s0, 0, 0, 0);
            s1 = __builtin_amdgcn_mfma_f32_32x32x16_f16(a1[ks], bQ[ks], s1, 0, 0, 0);
        }
        __builtin_amdgcn_s_setprio(0);

        // ---- defer-max online softmax (log2 domain), fully in-lane ----
        float fm = s0[0];
        #pragma unroll
        for (int r = 1; r < 16; ++r) fm = fmaxf(fm, s0[r]);
        #pragma unroll
        for (int r = 0; r < 16; ++r) fm = fmaxf(fm, s1[r]);

        if (!__all(fm <= m_run + 8.f)) {
            float fmf = fmaxf(fm, __shfl_xor(fm, 32));   // pair-lane: full row max
            float mn = fmaxf(m_run, fmf);
            float sc = exp2f(m_run - mn);
            m_run = mn;
            l_run *= sc;
            if (lane < 32) ScBuf[wid][lane] = sc;        // sc for softmax row i = lane
            #pragma unroll
            for (int r = 0; r < 16; ++r) {
                int irow = (r & 3) + 8 * (r >> 2) + 4 * hi;
                float scv = ScBuf[wid][irow];
                O0[r] *= scv; O1[r] *= scv;
            }
        }

        // ---- P = exp2(S - m): pack fp16 pairs, sum in-lane ----
        unsigned c0[8], c1[8];
        float ps = 0.f;
        #pragma unroll
        for (int m = 0; m < 8; ++m) {
            float pa = exp2f(s0[2 * m]     - m_run);
            float pb = exp2f(s0[2 * m + 1] - m_run);
            float pc = exp2f(s1[2 * m]     - m_run);
            float pd = exp2f(s1[2 * m + 1] - m_run);
            ps += (pa + pb) + (pc + pd);
            c0[m] = cvtpk(pa, pb);
            c1[m] = cvtpk(pc, pd);
        }
        l_run += ps;

        // ---- PV A-frags: lane's own words, zero exchange ----
        f16x8 pA[2][2];
        #pragma unroll
        for (int js = 0; js < 2; ++js) {
            unsigned* c = js ? c1 : c0;
            #pragma unroll
            for (int ksi = 0; ksi < 2; ++ksi) {
                uint32x4 w = { c[ksi * 4 + 0], c[ksi * 4 + 1], c[ksi * 4 + 2], c[ksi * 4 + 3] };
                pA[js][ksi] = __builtin_bit_cast(f16x8, w);
            }
        }

        // ---- PV: O[i][d] += P * V  (u = js*2 + ksi) ----
        __builtin_amdgcn_s_setprio(1);
        #pragma unroll
        for (int js = 0; js < 2; ++js) {
            #pragma unroll
            for (int ksi = 0; ksi < 2; ++ksi) {
                int u = js * 2 + ksi;
                O0 = __builtin_amdgcn_mfma_f32_32x32x16_f16(pA[js][ksi], vf0[u], O0, 0, 0, 0);
                O1 = __builtin_amdgcn_mfma_f32_32x32x16_f16(pA[js][ksi], vf1[u], O1, 0, 0, 0);
            }
        }
        __builtin_amdgcn_s_setprio(0);
    }

    // ---- epilogue: pair-sum l, LDS transpose, normalized coalesced store ----
    float l_full = l_run + __shfl_xor(l_run, 32);
    float invl = 1.0f / l_full;
    if (lane < 32) Lbuf[wid * 32 + lane] = invl;
    #pragma unroll
    for (int r = 0; r < 16; ++r) {
        int irow = (r & 3) + 8 * (r >> 2) + 4 * hi;
        int ilocal = wid * 32 + irow;
        Epi[(l31) * 132 + ilocal]      = O0[r];
        Epi[(32 + l31) * 132 + ilocal] = O1[r];
    }
    __syncthreads();
    float* ob = out + ((size_t)b * CH + h * DH) * NN + i0;
    #pragma unroll
    for (int rep = 0; rep < 8; ++rep) {
        int f = rep * 256 + tid;
        int d = f >> 5, q = f & 31;
        float4 v4 = *(const float4*)&Epi[d * 132 + q * 4];
        float4 iv = *(const float4*)&Lbuf[q * 4];
        v4.x *= iv.x; v4.y *= iv.y; v4.z *= iv.z; v4.w *= iv.w;
        *(float4*)&ob[(size_t)d * NN + q * 4] = v4;
    }
}

extern "C" void kernel_launch(void* const* d_in, const int* in_sizes, int n_in,
                              void* d_out, int out_size, void* d_ws, size_t ws_size,
                              hipStream_t stream) {
    const float* x     = (const float*)d_in[0];
    const float* Wq    = (const float*)d_in[1];
    const float* bq    = (const float*)d_in[2];
    const float* Wk    = (const float*)d_in[3];
    const float* bk    = (const float*)d_in[4];
    const float* Wv    = (const float*)d_in[5];
    const float* bv    = (const float*)d_in[6];
    const float* rel_h = (const float*)d_in[7];
    const float* rel_w = (const float*)d_in[8];
    // d_in[9] (reg_qk), d_in[10] (reg_v): dead — reference discards the register-token group.
    float* out = (float*)d_out;

    unsigned short* kF = (unsigned short*)d_ws;                 // 8,388,608 halves (16.8MB)
    unsigned short* vF = kF + (size_t)8388608;                  // 4,194,304 (8.4MB)
    unsigned short* xT = vF + (size_t)4194304;                  // 4,194,304 (8.4MB)
    unsigned short* Wh = xT + (size_t)4194304;                  // 196,608 — 34.0MB total

    prepxt_kernel<<<dim3(4096 + 768), 256, 0, stream>>>(x, Wq, Wk, Wv, xT, Wh);
    proj_kernel<<<dim3(16, 4, 48), 256, 0, stream>>>(
        xT, Wh, bq, bk, bv, kF, vF);
    attn_kernel<<<dim3(512), 256, 0, stream>>>(kF, vF, rel_h, rel_w, out);
}